// Round 10
// baseline (78.509 us; speedup 1.0000x reference)
//
#include <hip/hip_runtime.h>

#define M_DIM 32
#define K_DIM 4096
#define N_DIM 12288
#define SPLITK 8
#define KPER  (K_DIM / SPLITK)     // 512 k per block
#define NT    (KPER / 32)          // 16 k-tiles of 32
#define BLK   512                  // 8 waves
#define NPB   128                  // n per block (8 waves x 16)

using bf16x8 = __attribute__((ext_vector_type(8))) short;
using f32x4  = __attribute__((ext_vector_type(4))) float;

typedef __attribute__((address_space(1))) const void GASV;
typedef __attribute__((address_space(3))) void LASV;

__device__ __forceinline__ short to_bf16(float f) {
    unsigned u = __float_as_uint(f);
    u += 0x7FFFu + ((u >> 16) & 1u);               // RNE
    return (short)(u >> 16);
}

// ints in [0,256) are exact in bf16; f32 mantissa bits [15:0] are zero -> take high16.
__device__ __forceinline__ bf16x8 pack_b(const int (&wv)[8]) {
    union { unsigned u[4]; bf16x8 v; } r;
    #pragma unroll
    for (int p = 0; p < 4; ++p) {
        unsigned a = __float_as_uint((float)wv[2 * p]);
        unsigned b = __float_as_uint((float)wv[2 * p + 1]);
        r.u[p] = __builtin_amdgcn_perm(b, a, 0x07060302);  // [b.hi16 | a.hi16]
    }
    return r.v;
}

// ---------------------------------------------------------------------------
// Prep: all A-fragments once (256 KB) + rowsum. UNCHANGED from round 9.
// ---------------------------------------------------------------------------
__global__ __launch_bounds__(256) void qmm_prep(const float* __restrict__ x,
                                                short* __restrict__ frag,
                                                float* __restrict__ rowsum) {
    const int b   = blockIdx.x;                    // 0..31
    const int tid = threadIdx.x;

    __shared__ float red[256];
    const float4* xr = (const float4*)(x + (size_t)b * K_DIM);
    float s = 0.f;
    #pragma unroll
    for (int i = 0; i < K_DIM / 4 / 256; ++i) {
        float4 v = xr[tid + 256 * i];
        s += v.x + v.y + v.z + v.w;
    }
    red[tid] = s;
    __syncthreads();
    #pragma unroll
    for (int off = 128; off > 0; off >>= 1) {
        if (tid < off) red[tid] += red[tid + off];
        __syncthreads();
    }
    if (tid == 0) rowsum[b] = red[0];

    #pragma unroll
    for (int i = 0; i < 2; ++i) {
        const int s2   = i * 256 + tid;            // 0..511
        const int kt   = 4 * b + (s2 >> 7);
        const int h    = (s2 >> 6) & 1;
        const int lane = s2 & 63;
        const int g    = lane >> 4;
        const int g0   = g & 1;
        const int m    = 16 * h + (lane & 15);
        const float* xp = x + (size_t)m * K_DIM + kt * 32 + 8 * g;
        float p0 = xp[0], p1 = xp[1], p2 = xp[2], p3 = xp[3];
        float p4 = xp[4], p5 = xp[5], p6 = xp[6], p7 = xp[7];
        bf16x8 v;
        v[0] = to_bf16(g0 ? p1 : p0);  v[1] = to_bf16(g0 ? p0 : p1);
        v[2] = to_bf16(g0 ? p3 : p2);  v[3] = to_bf16(g0 ? p2 : p3);
        v[4] = to_bf16(g0 ? p5 : p4);  v[5] = to_bf16(g0 ? p4 : p5);
        v[6] = to_bf16(g0 ? p7 : p6);  v[7] = to_bf16(g0 ? p6 : p7);
        *(bf16x8*)&frag[(size_t)((kt * 2 + h) * 64 + lane) * 8] = v;
    }
}

// ---------------------------------------------------------------------------
// Main: UNCHANGED from round 9 (frozen for clean probe subtraction).
// ---------------------------------------------------------------------------
template <bool WS>
__global__ __launch_bounds__(BLK, 4) void qmm_main(const short* __restrict__ frag,
                                                   const int* __restrict__ w,
                                                   float* __restrict__ dst) {
    __shared__ int lds_b[8 * 2 * 512];             // 32 KB: 8 waves x ring2 x 2KB

    const int tid  = threadIdx.x;
    const int lane = tid & 63;
    const int g    = lane >> 4;
    const int g0   = g & 1;
    const int c    = lane & 15;
    const int wid  = tid >> 6;
    const int k0   = blockIdx.y * KPER;
    const int n0w  = blockIdx.x * NPB + wid * 16;

    const int* gsrc[2];
    #pragma unroll
    for (int q = 0; q < 2; ++q)
        gsrc[q] = w + (size_t)(k0 + 16 * q + (lane >> 2)) * N_DIM + n0w + 4 * (lane & 3);

    int* const wbase = &lds_b[wid * 1024];

    const int vb = 4 * (128 * g + 4 * (c >> 2) + (c & 3));
    const int be = vb + 64 * g0;
    const int bo = vb + 64 * (1 - g0);

    const short* asrc = frag + ((size_t)(blockIdx.y * NT) * 1024 + lane * 8);

    f32x4 acc0 = {0.f, 0.f, 0.f, 0.f};
    f32x4 acc1 = {0.f, 0.f, 0.f, 0.f};
    bf16x8 aA0, aA1, aB0, aB1;

#define ISSUE(T) do {                                                            \
    __builtin_amdgcn_sched_barrier(0);                                           \
    __builtin_amdgcn_global_load_lds((GASV*)(gsrc[0] + (size_t)(32 * (T)) * N_DIM), \
        (LASV*)(wbase + ((T) & 1) * 512),       16, 0, 0);                       \
    __builtin_amdgcn_global_load_lds((GASV*)(gsrc[1] + (size_t)(32 * (T)) * N_DIM), \
        (LASV*)(wbase + ((T) & 1) * 512 + 256), 16, 0, 0);                       \
    if ((T) & 1) { aB0 = *(const bf16x8*)(asrc + (T) * 1024);                    \
                   aB1 = *(const bf16x8*)(asrc + (T) * 1024 + 512); }            \
    else         { aA0 = *(const bf16x8*)(asrc + (T) * 1024);                    \
                   aA1 = *(const bf16x8*)(asrc + (T) * 1024 + 512); }            \
    __builtin_amdgcn_sched_barrier(0);                                           \
} while (0)

#define WAITV(N) do { asm volatile("s_waitcnt vmcnt(" #N ")" ::: "memory");      \
    __builtin_amdgcn_sched_barrier(0); } while (0)

#define COMP(T) do {                                                             \
    char* pb = (char*)wbase + ((T) & 1) * 2048;                                  \
    int wv[8];                                                                   \
    wv[0] = *(int*)(pb + be);        wv[1] = *(int*)(pb + bo);                   \
    wv[2] = *(int*)(pb + be + 128);  wv[3] = *(int*)(pb + bo + 128);             \
    wv[4] = *(int*)(pb + be + 256);  wv[5] = *(int*)(pb + bo + 256);             \
    wv[6] = *(int*)(pb + be + 384);  wv[7] = *(int*)(pb + bo + 384);             \
    bf16x8 bfv = pack_b(wv);                                                     \
    acc0 = __builtin_amdgcn_mfma_f32_16x16x32_bf16(((T) & 1) ? aB0 : aA0, bfv, acc0, 0, 0, 0); \
    acc1 = __builtin_amdgcn_mfma_f32_16x16x32_bf16(((T) & 1) ? aB1 : aA1, bfv, acc1, 0, 0, 0); \
} while (0)

    ISSUE(0); ISSUE(1);
    WAITV(4); COMP(0);  ISSUE(2);
    WAITV(4); COMP(1);  ISSUE(3);
    WAITV(4); COMP(2);  ISSUE(4);
    WAITV(4); COMP(3);  ISSUE(5);
    WAITV(4); COMP(4);  ISSUE(6);
    WAITV(4); COMP(5);  ISSUE(7);
    WAITV(4); COMP(6);  ISSUE(8);
    WAITV(4); COMP(7);  ISSUE(9);
    WAITV(4); COMP(8);  ISSUE(10);
    WAITV(4); COMP(9);  ISSUE(11);
    WAITV(4); COMP(10); ISSUE(12);
    WAITV(4); COMP(11); ISSUE(13);
    WAITV(4); COMP(12); ISSUE(14);
    WAITV(4); COMP(13); ISSUE(15);
    WAITV(4); COMP(14);
    WAITV(0); COMP(15);

#undef ISSUE
#undef WAITV
#undef COMP

    if (WS) {
        float* pp = dst + ((size_t)blockIdx.y * M_DIM) * N_DIM + n0w + c;
        #pragma unroll
        for (int i = 0; i < 4; ++i) {
            const int r = 4 * (lane >> 4) + i;
            pp[(size_t)r * N_DIM]        = acc0[i];
            pp[(size_t)(16 + r) * N_DIM] = acc1[i];
        }
    } else {
        #pragma unroll
        for (int i = 0; i < 4; ++i) {
            const int r = 4 * (lane >> 4) + i;
            atomicAdd(&dst[(size_t)r * N_DIM + n0w + c], acc0[i]);
            atomicAdd(&dst[(size_t)(16 + r) * N_DIM + n0w + c], acc1[i]);
        }
    }
}

// Finalize: UNCHANGED from round 9.
__global__ __launch_bounds__(256) void qmm_finalize(const float* __restrict__ part,
                                                    const float* __restrict__ rowsum,
                                                    const float* __restrict__ scale,
                                                    const float* __restrict__ zero,
                                                    float* __restrict__ out) {
    const int m  = blockIdx.y;
    const int n4 = blockIdx.x * 256 + threadIdx.x;
    const float rs = rowsum[m];
    float4 acc = make_float4(0.f, 0.f, 0.f, 0.f);
    #pragma unroll
    for (int sp = 0; sp < SPLITK; ++sp) {
        float4 p = ((const float4*)(part + ((size_t)sp * M_DIM + m) * N_DIM))[n4];
        acc.x += p.x; acc.y += p.y; acc.z += p.z; acc.w += p.w;
    }
    const float4 sc = ((const float4*)scale)[n4];
    const float4 zp = ((const float4*)zero)[n4];
    float4 o;
    o.x = sc.x * (acc.x - zp.x * rs);
    o.y = sc.y * (acc.y - zp.y * rs);
    o.z = sc.z * (acc.z - zp.z * rs);
    o.w = sc.w * (acc.w - zp.w * rs);
    ((float4*)(out + (size_t)m * N_DIM))[n4] = o;
}

// ---------------------------------------------------------------------------
// PROBE (instrumentation, this round only): pure streaming read of ALL of w,
// grid-stride int4, per-thread sink. Measures the empirical delivery rate of
// the 192 MiB weight buffer in the same graph/L3 state main sees.
// t_probe = timed_total - 46.0us (round-9 baseline, kernels above frozen).
// ---------------------------------------------------------------------------
__global__ __launch_bounds__(256) void qmm_probe(const int4* __restrict__ w4,
                                                 float* __restrict__ sink) {
    const size_t stride = (size_t)gridDim.x * 256;
    size_t i = (size_t)blockIdx.x * 256 + threadIdx.x;
    int s = 0;
    for (size_t p = i; p < (size_t)K_DIM * N_DIM / 4; p += stride) {
        int4 v = w4[p];
        s += v.x + v.y + v.z + v.w;
    }
    sink[i] = (float)s;
}

// Fallback path (ws too small): unchanged.
__global__ __launch_bounds__(256) void qmm_zero(float* __restrict__ out) {
    int i = blockIdx.x * 256 + threadIdx.x;
    ((float4*)out)[i] = make_float4(0.f, 0.f, 0.f, 0.f);
}
__global__ __launch_bounds__(256) void qmm_scale(const float* __restrict__ x,
                                                 const float* __restrict__ scale,
                                                 const float* __restrict__ zero,
                                                 float* __restrict__ out) {
    const int m = blockIdx.y;
    __shared__ float red[256];
    float s = 0.f;
    for (int k = threadIdx.x; k < K_DIM; k += 256)
        s += x[(size_t)m * K_DIM + k];
    red[threadIdx.x] = s;
    __syncthreads();
    #pragma unroll
    for (int off = 128; off > 0; off >>= 1) {
        if (threadIdx.x < off) red[threadIdx.x] += red[threadIdx.x + off];
        __syncthreads();
    }
    const float rowsum = red[0];
    const int n = blockIdx.x * 256 + threadIdx.x;
    const float v = out[(size_t)m * N_DIM + n];
    out[(size_t)m * N_DIM + n] = scale[n] * (v - zero[n] * rowsum);
}

extern "C" void kernel_launch(void* const* d_in, const int* in_sizes, int n_in,
                              void* d_out, int out_size, void* d_ws, size_t ws_size,
                              hipStream_t stream) {
    const float* x     = (const float*)d_in[0];
    const int*   w     = (const int*)d_in[1];
    const float* scale = (const float*)d_in[2];   // fp16 in reference; harness delivers fp32
    const float* zero  = (const float*)d_in[3];
    float* out = (float*)d_out;

    const size_t frag_sz = (size_t)128 * 2 * 64 * 8 * sizeof(short);            // 256 KB
    const size_t part_sz = (size_t)SPLITK * M_DIM * N_DIM * sizeof(float);      // 12.6 MB
    short* fragp  = (short*)d_ws;
    float* rowsum = (float*)((char*)d_ws + frag_sz);
    float* part   = (float*)((char*)d_ws + frag_sz + 256);
    float* sink   = (float*)((char*)d_ws + (64u << 20));                        // 64 MB off

    if (ws_size >= frag_sz + 256 + part_sz) {
        qmm_prep    <<<dim3(32),                 dim3(256), 0, stream>>>(x, fragp, rowsum);
        qmm_main<true><<<dim3(N_DIM / NPB, SPLITK), dim3(BLK), 0, stream>>>(fragp, w, part);
        qmm_finalize<<<dim3(N_DIM / 4 / 256, M_DIM), dim3(256), 0, stream>>>(part, rowsum, scale, zero, out);
        if (ws_size >= (64u << 20) + (size_t)2048 * 256 * sizeof(float))
            qmm_probe<<<dim3(2048), dim3(256), 0, stream>>>((const int4*)w, sink);
    } else {
        qmm_prep    <<<dim3(32),                 dim3(256), 0, stream>>>(x, fragp, rowsum);
        qmm_zero    <<<dim3((M_DIM * N_DIM / 4) / 256), dim3(256), 0, stream>>>(out);
        qmm_main<false><<<dim3(N_DIM / NPB, SPLITK), dim3(BLK), 0, stream>>>(fragp, w, out);
        qmm_scale   <<<dim3(N_DIM / 256, M_DIM), dim3(256), 0, stream>>>(x, scale, zero, out);
    }
}

// Round 11
// 43.166 us; speedup vs baseline: 1.8188x; 1.8188x over previous
//
#include <hip/hip_runtime.h>

#define M_DIM 32
#define K_DIM 4096
#define N_DIM 12288
#define SPLITK 8
#define KPER  (K_DIM / SPLITK)     // 512 k per block
#define NT    (KPER / 32)          // 16 k-tiles of 32
#define BLK   512                  // 8 waves
#define NPB   128                  // n per block (8 waves x 16)

using bf16x8 = __attribute__((ext_vector_type(8))) short;
using f32x4  = __attribute__((ext_vector_type(4))) float;

typedef __attribute__((address_space(1))) const void GASV;
typedef __attribute__((address_space(3))) void LASV;

__device__ __forceinline__ short to_bf16(float f) {
    unsigned u = __float_as_uint(f);
    u += 0x7FFFu + ((u >> 16) & 1u);               // RNE
    return (short)(u >> 16);
}

// ints in [0,256) are exact in bf16; f32 mantissa bits [15:0] are zero -> take high16.
__device__ __forceinline__ bf16x8 pack_b(const int (&wv)[8]) {
    union { unsigned u[4]; bf16x8 v; } r;
    #pragma unroll
    for (int p = 0; p < 4; ++p) {
        unsigned a = __float_as_uint((float)wv[2 * p]);
        unsigned b = __float_as_uint((float)wv[2 * p + 1]);
        r.u[p] = __builtin_amdgcn_perm(b, a, 0x07060302);  // [b.hi16 | a.hi16]
    }
    return r.v;
}

// ---------------------------------------------------------------------------
// Prep+zero (fused): all 384 blocks zero a float4-chunk of out (atomics in
// main need a clean accumulator each call); blocks 0..31 also build the
// A-fragments (256 KB) and rowsum. A-build identical to round 9.
// ---------------------------------------------------------------------------
__global__ __launch_bounds__(256) void qmm_prep(const float* __restrict__ x,
                                                short* __restrict__ frag,
                                                float* __restrict__ rowsum,
                                                float* __restrict__ out) {
    const int tid = threadIdx.x;
    const int bid = blockIdx.x;

    ((float4*)out)[bid * 256 + tid] = make_float4(0.f, 0.f, 0.f, 0.f);
    if (bid >= 32) return;
    const int b = bid;                             // 0..31

    __shared__ float red[256];
    const float4* xr = (const float4*)(x + (size_t)b * K_DIM);
    float s = 0.f;
    #pragma unroll
    for (int i = 0; i < K_DIM / 4 / 256; ++i) {
        float4 v = xr[tid + 256 * i];
        s += v.x + v.y + v.z + v.w;
    }
    red[tid] = s;
    __syncthreads();
    #pragma unroll
    for (int off = 128; off > 0; off >>= 1) {
        if (tid < off) red[tid] += red[tid + off];
        __syncthreads();
    }
    if (tid == 0) rowsum[b] = red[0];

    #pragma unroll
    for (int i = 0; i < 2; ++i) {
        const int s2   = i * 256 + tid;            // 0..511
        const int kt   = 4 * b + (s2 >> 7);
        const int h    = (s2 >> 6) & 1;
        const int lane = s2 & 63;
        const int g    = lane >> 4;
        const int g0   = g & 1;
        const int m    = 16 * h + (lane & 15);
        const float* xp = x + (size_t)m * K_DIM + kt * 32 + 8 * g;
        float p0 = xp[0], p1 = xp[1], p2 = xp[2], p3 = xp[3];
        float p4 = xp[4], p5 = xp[5], p6 = xp[6], p7 = xp[7];
        bf16x8 v;
        v[0] = to_bf16(g0 ? p1 : p0);  v[1] = to_bf16(g0 ? p0 : p1);
        v[2] = to_bf16(g0 ? p3 : p2);  v[3] = to_bf16(g0 ? p2 : p3);
        v[4] = to_bf16(g0 ? p5 : p4);  v[5] = to_bf16(g0 ? p4 : p5);
        v[6] = to_bf16(g0 ? p7 : p6);  v[7] = to_bf16(g0 ? p6 : p7);
        *(bf16x8*)&frag[(size_t)((kt * 2 + h) * 64 + lane) * 8] = v;
    }
}

// ---------------------------------------------------------------------------
// Main: K-loop frozen from round 9 (probe-validated at ~90% of wire).
// Epilogue now FUSED: each slice atomicAdds scale[n]*acc; slice 0 also adds
// the -scale[n]*zero[n]*rowsum[m] correction. No partials, no finalize.
// ---------------------------------------------------------------------------
__global__ __launch_bounds__(BLK, 4) void qmm_main(const short* __restrict__ frag,
                                                   const int* __restrict__ w,
                                                   const float* __restrict__ rowsum,
                                                   const float* __restrict__ scale,
                                                   const float* __restrict__ zero,
                                                   float* __restrict__ out) {
    __shared__ int lds_b[8 * 2 * 512];             // 32 KB: 8 waves x ring2 x 2KB

    const int tid  = threadIdx.x;
    const int lane = tid & 63;
    const int g    = lane >> 4;
    const int g0   = g & 1;
    const int c    = lane & 15;
    const int wid  = tid >> 6;
    const int k0   = blockIdx.y * KPER;
    const int n0w  = blockIdx.x * NPB + wid * 16;

    const int* gsrc[2];
    #pragma unroll
    for (int q = 0; q < 2; ++q)
        gsrc[q] = w + (size_t)(k0 + 16 * q + (lane >> 2)) * N_DIM + n0w + 4 * (lane & 3);

    int* const wbase = &lds_b[wid * 1024];

    const int vb = 4 * (128 * g + 4 * (c >> 2) + (c & 3));
    const int be = vb + 64 * g0;
    const int bo = vb + 64 * (1 - g0);

    const short* asrc = frag + ((size_t)(blockIdx.y * NT) * 1024 + lane * 8);

    f32x4 acc0 = {0.f, 0.f, 0.f, 0.f};            // m in [0,16)
    f32x4 acc1 = {0.f, 0.f, 0.f, 0.f};            // m in [16,32)
    bf16x8 aA0, aA1, aB0, aB1;

#define ISSUE(T) do {                                                            \
    __builtin_amdgcn_sched_barrier(0);                                           \
    __builtin_amdgcn_global_load_lds((GASV*)(gsrc[0] + (size_t)(32 * (T)) * N_DIM), \
        (LASV*)(wbase + ((T) & 1) * 512),       16, 0, 0);                       \
    __builtin_amdgcn_global_load_lds((GASV*)(gsrc[1] + (size_t)(32 * (T)) * N_DIM), \
        (LASV*)(wbase + ((T) & 1) * 512 + 256), 16, 0, 0);                       \
    if ((T) & 1) { aB0 = *(const bf16x8*)(asrc + (T) * 1024);                    \
                   aB1 = *(const bf16x8*)(asrc + (T) * 1024 + 512); }            \
    else         { aA0 = *(const bf16x8*)(asrc + (T) * 1024);                    \
                   aA1 = *(const bf16x8*)(asrc + (T) * 1024 + 512); }            \
    __builtin_amdgcn_sched_barrier(0);                                           \
} while (0)

#define WAITV(N) do { asm volatile("s_waitcnt vmcnt(" #N ")" ::: "memory");      \
    __builtin_amdgcn_sched_barrier(0); } while (0)

#define COMP(T) do {                                                             \
    char* pb = (char*)wbase + ((T) & 1) * 2048;                                  \
    int wv[8];                                                                   \
    wv[0] = *(int*)(pb + be);        wv[1] = *(int*)(pb + bo);                   \
    wv[2] = *(int*)(pb + be + 128);  wv[3] = *(int*)(pb + bo + 128);             \
    wv[4] = *(int*)(pb + be + 256);  wv[5] = *(int*)(pb + bo + 256);             \
    wv[6] = *(int*)(pb + be + 384);  wv[7] = *(int*)(pb + bo + 384);             \
    bf16x8 bfv = pack_b(wv);                                                     \
    acc0 = __builtin_amdgcn_mfma_f32_16x16x32_bf16(((T) & 1) ? aB0 : aA0, bfv, acc0, 0, 0, 0); \
    acc1 = __builtin_amdgcn_mfma_f32_16x16x32_bf16(((T) & 1) ? aB1 : aA1, bfv, acc1, 0, 0, 0); \
} while (0)

    ISSUE(0); ISSUE(1);
    WAITV(4); COMP(0);  ISSUE(2);
    WAITV(4); COMP(1);  ISSUE(3);
    WAITV(4); COMP(2);  ISSUE(4);
    WAITV(4); COMP(3);  ISSUE(5);
    WAITV(4); COMP(4);  ISSUE(6);
    WAITV(4); COMP(5);  ISSUE(7);
    WAITV(4); COMP(6);  ISSUE(8);
    WAITV(4); COMP(7);  ISSUE(9);
    WAITV(4); COMP(8);  ISSUE(10);
    WAITV(4); COMP(9);  ISSUE(11);
    WAITV(4); COMP(10); ISSUE(12);
    WAITV(4); COMP(11); ISSUE(13);
    WAITV(4); COMP(12); ISSUE(14);
    WAITV(4); COMP(13); ISSUE(15);
    WAITV(4); COMP(14);
    WAITV(0); COMP(15);

#undef ISSUE
#undef WAITV
#undef COMP

    // Fused epilogue. C/D layout (HW-verified): row = 4*(lane>>4)+i, col = lane&15.
    // out += sc*acc  (+ slice0: -sc*zp*rowsum[m])
    const float sc = scale[n0w + c];
    float corr0[4] = {0.f, 0.f, 0.f, 0.f}, corr1[4] = {0.f, 0.f, 0.f, 0.f};
    if (blockIdx.y == 0) {
        const float zp = zero[n0w + c];
        #pragma unroll
        for (int i = 0; i < 4; ++i) {
            const int r = 4 * (lane >> 4) + i;
            corr0[i] = zp * rowsum[r];
            corr1[i] = zp * rowsum[16 + r];
        }
    }
    #pragma unroll
    for (int i = 0; i < 4; ++i) {
        const int r = 4 * (lane >> 4) + i;
        atomicAdd(&out[(size_t)r * N_DIM + n0w + c],        sc * (acc0[i] - corr0[i]));
        atomicAdd(&out[(size_t)(16 + r) * N_DIM + n0w + c], sc * (acc1[i] - corr1[i]));
    }
}

// ---------------------------------------------------------------------------
// Fallback path (ws too small for frag; never expected with 768 MB ws):
// round-3-proven scalar route, self-contained.
// ---------------------------------------------------------------------------
__global__ __launch_bounds__(256) void qmm_zero_fb(float* __restrict__ out) {
    int i = blockIdx.x * 256 + threadIdx.x;
    ((float4*)out)[i] = make_float4(0.f, 0.f, 0.f, 0.f);
}
__global__ __launch_bounds__(256) void qmm_main_fb(const float* __restrict__ x,
                                                   const int* __restrict__ w,
                                                   float* __restrict__ out) {
    const int n  = blockIdx.x * 256 + threadIdx.x;
    const int k0 = blockIdx.y * 256;
    float acc[M_DIM];
    #pragma unroll
    for (int m = 0; m < M_DIM; ++m) acc[m] = 0.f;
    const int* wp = w + (size_t)k0 * N_DIM + n;
    for (int kk = 0; kk < 256; kk += 4) {
        const float w0 = (float)wp[(size_t)(kk + 0) * N_DIM];
        const float w1 = (float)wp[(size_t)(kk + 1) * N_DIM];
        const float w2 = (float)wp[(size_t)(kk + 2) * N_DIM];
        const float w3 = (float)wp[(size_t)(kk + 3) * N_DIM];
        #pragma unroll
        for (int m = 0; m < M_DIM; ++m) {
            const float4 xv = *(const float4*)(x + (size_t)m * K_DIM + k0 + kk);
            acc[m] = fmaf(xv.x, w0, fmaf(xv.y, w1, fmaf(xv.z, w2, fmaf(xv.w, w3, acc[m]))));
        }
    }
    #pragma unroll
    for (int m = 0; m < M_DIM; ++m)
        atomicAdd(&out[(size_t)m * N_DIM + n], acc[m]);
}
__global__ __launch_bounds__(256) void qmm_scale_fb(const float* __restrict__ x,
                                                    const float* __restrict__ scale,
                                                    const float* __restrict__ zero,
                                                    float* __restrict__ out) {
    const int m = blockIdx.y;
    __shared__ float red[256];
    float s = 0.f;
    for (int k = threadIdx.x; k < K_DIM; k += 256)
        s += x[(size_t)m * K_DIM + k];
    red[threadIdx.x] = s;
    __syncthreads();
    #pragma unroll
    for (int off = 128; off > 0; off >>= 1) {
        if (threadIdx.x < off) red[threadIdx.x] += red[threadIdx.x + off];
        __syncthreads();
    }
    const float rowsum = red[0];
    const int n = blockIdx.x * 256 + threadIdx.x;
    const float v = out[(size_t)m * N_DIM + n];
    out[(size_t)m * N_DIM + n] = scale[n] * (v - zero[n] * rowsum);
}

extern "C" void kernel_launch(void* const* d_in, const int* in_sizes, int n_in,
                              void* d_out, int out_size, void* d_ws, size_t ws_size,
                              hipStream_t stream) {
    const float* x     = (const float*)d_in[0];
    const int*   w     = (const int*)d_in[1];
    const float* scale = (const float*)d_in[2];   // fp16 in reference; harness delivers fp32
    const float* zero  = (const float*)d_in[3];
    float* out = (float*)d_out;

    const size_t frag_sz = (size_t)128 * 2 * 64 * 8 * sizeof(short);  // 256 KB
    short* fragp  = (short*)d_ws;
    float* rowsum = (float*)((char*)d_ws + frag_sz);

    if (ws_size >= frag_sz + 256) {
        qmm_prep<<<dim3(M_DIM * N_DIM / 4 / 256), dim3(256), 0, stream>>>(x, fragp, rowsum, out);
        qmm_main<<<dim3(N_DIM / NPB, SPLITK),     dim3(BLK), 0, stream>>>(fragp, w, rowsum, scale, zero, out);
    } else {
        qmm_zero_fb <<<dim3(M_DIM * N_DIM / 4 / 256), dim3(256), 0, stream>>>(out);
        qmm_main_fb <<<dim3(N_DIM / 256, 16),         dim3(256), 0, stream>>>(x, w, out);
        qmm_scale_fb<<<dim3(N_DIM / 256, M_DIM),      dim3(256), 0, stream>>>(x, scale, zero, out);
    }
}

// Round 12
// 43.051 us; speedup vs baseline: 1.8236x; 1.0027x over previous
//
#include <hip/hip_runtime.h>

#define M_DIM 32
#define K_DIM 4096
#define N_DIM 12288
#define SPLITK 8
#define KPER  (K_DIM / SPLITK)     // 512 k per block
#define NT    (KPER / 32)          // 16 k-tiles of 32
#define BLK   512                  // 8 waves
#define NPB   128                  // n per block (8 waves x 16)

using bf16x8 = __attribute__((ext_vector_type(8))) short;
using f32x4  = __attribute__((ext_vector_type(4))) float;

typedef __attribute__((address_space(1))) const void GASV;
typedef __attribute__((address_space(3))) void LASV;

__device__ __forceinline__ short to_bf16(float f) {
    unsigned u = __float_as_uint(f);
    u += 0x7FFFu + ((u >> 16) & 1u);               // RNE
    return (short)(u >> 16);
}

// ints in [0,256) are exact in bf16; f32 mantissa bits [15:0] are zero -> take high16.
__device__ __forceinline__ bf16x8 pack_b(const int (&wv)[8]) {
    union { unsigned u[4]; bf16x8 v; } r;
    #pragma unroll
    for (int p = 0; p < 4; ++p) {
        unsigned a = __float_as_uint((float)wv[2 * p]);
        unsigned b = __float_as_uint((float)wv[2 * p + 1]);
        r.u[p] = __builtin_amdgcn_perm(b, a, 0x07060302);  // [b.hi16 | a.hi16]
    }
    return r.v;
}

// ---------------------------------------------------------------------------
// Prep+zero (fused): all 384 blocks zero a float4-chunk of out; blocks 0..31
// also build A-fragments (256 KB) + rowsum. IDENTITY k-map now (elem j of
// lane-group g holds k = kt*32 + 8g + j) to match main's straight j read.
// ---------------------------------------------------------------------------
__global__ __launch_bounds__(256) void qmm_prep(const float* __restrict__ x,
                                                short* __restrict__ frag,
                                                float* __restrict__ rowsum,
                                                float* __restrict__ out) {
    const int tid = threadIdx.x;
    const int bid = blockIdx.x;

    ((float4*)out)[bid * 256 + tid] = make_float4(0.f, 0.f, 0.f, 0.f);
    if (bid >= 32) return;
    const int b = bid;                             // 0..31

    __shared__ float red[256];
    const float4* xr = (const float4*)(x + (size_t)b * K_DIM);
    float s = 0.f;
    #pragma unroll
    for (int i = 0; i < K_DIM / 4 / 256; ++i) {
        float4 v = xr[tid + 256 * i];
        s += v.x + v.y + v.z + v.w;
    }
    red[tid] = s;
    __syncthreads();
    #pragma unroll
    for (int off = 128; off > 0; off >>= 1) {
        if (tid < off) red[tid] += red[tid + off];
        __syncthreads();
    }
    if (tid == 0) rowsum[b] = red[0];

    #pragma unroll
    for (int i = 0; i < 2; ++i) {
        const int s2   = i * 256 + tid;            // 0..511
        const int kt   = 4 * b + (s2 >> 7);
        const int h    = (s2 >> 6) & 1;
        const int lane = s2 & 63;
        const int g    = lane >> 4;
        const int m    = 16 * h + (lane & 15);
        const float* xp = x + (size_t)m * K_DIM + kt * 32 + 8 * g;
        bf16x8 v;
        #pragma unroll
        for (int j = 0; j < 8; ++j) v[j] = to_bf16(xp[j]);
        *(bf16x8*)&frag[(size_t)((kt * 2 + h) * 64 + lane) * 8] = v;
    }
}

// ---------------------------------------------------------------------------
// Main: block-cooperative contiguous staging. Each tile (32 rows x 128 cols,
// 16 KB) staged by 16 global_load_lds instrs of 1 KiB covering 2 FULL rows
// each (2x512B segments vs old 16x64B) -> ~8x fewer memory requests/byte.
// Source col XOR-swizzled (involution, 16B-granule):  colgran ^= g|((g&1)<<2)
// so each ds_read_b32 is 2-way banked (free). Double-buffered, one
// __syncthreads per tile (r7-vs-r8 showed barriers are not the limiter).
// Epilogue fused (scale + zero/rowsum correction, atomicAdd).
// ---------------------------------------------------------------------------
__global__ __launch_bounds__(BLK, 4) void qmm_main(const short* __restrict__ frag,
                                                   const int* __restrict__ w,
                                                   const float* __restrict__ rowsum,
                                                   const float* __restrict__ scale,
                                                   const float* __restrict__ zero,
                                                   float* __restrict__ out) {
    __shared__ int lds_b[2 * 32 * 128];            // 2 x 16 KB tiles

    const int tid  = threadIdx.x;
    const int lane = tid & 63;
    const int g    = lane >> 4;
    const int c    = lane & 15;
    const int wid  = tid >> 6;
    const int k0   = blockIdx.y * KPER;
    const int n0   = blockIdx.x * NPB;
    const int n0w  = n0 + wid * 16;

    // staging source: instr q covers local rows 4wid+2q + (lane>>5); within a
    // row, lane covers 16B granule (lane&31) XOR sw(row)  [involution]
    const int* gs[2];
    #pragma unroll
    for (int q = 0; q < 2; ++q) {
        const int rl = 4 * wid + 2 * q + (lane >> 5);
        const int gg = (rl >> 3) & 3;
        const int sw = gg | ((gg & 1) << 2);
        gs[q] = w + (size_t)(k0 + rl) * N_DIM + n0 + 4 * ((lane & 31) ^ sw);
    }
    int* const ld0 = &lds_b[(wid * 2 + 0) * 256];
    int* const ld1 = &lds_b[(wid * 2 + 1) * 256];

    // read base (dwords): row 8g, swizzled col position
    const int prd = (wid * 16 + c) ^ (g << 2) ^ ((g & 1) << 4);
    const int* const bq = lds_b + g * 8 * 128 + prd;

    const short* asrc = frag + ((size_t)(blockIdx.y * NT) * 1024 + lane * 8);

    f32x4 acc0 = {0.f, 0.f, 0.f, 0.f};            // m in [0,16)
    f32x4 acc1 = {0.f, 0.f, 0.f, 0.f};            // m in [16,32)
    bf16x8 aA0, aA1, aB0, aB1;

#define STAGE(T) do { if ((T) < NT) {                                            \
    __builtin_amdgcn_global_load_lds((GASV*)(gs[0] + (size_t)(32 * (T)) * N_DIM), \
        (LASV*)(ld0 + ((T) & 1) * 4096), 16, 0, 0);                              \
    __builtin_amdgcn_global_load_lds((GASV*)(gs[1] + (size_t)(32 * (T)) * N_DIM), \
        (LASV*)(ld1 + ((T) & 1) * 4096), 16, 0, 0);                              \
} } while (0)

#define LOADA(T) do { if ((T) < NT) {                                            \
    if ((T) & 1) { aB0 = *(const bf16x8*)(asrc + (size_t)(T) * 1024);            \
                   aB1 = *(const bf16x8*)(asrc + (size_t)(T) * 1024 + 512); }    \
    else         { aA0 = *(const bf16x8*)(asrc + (size_t)(T) * 1024);            \
                   aA1 = *(const bf16x8*)(asrc + (size_t)(T) * 1024 + 512); }    \
} } while (0)

#define COMP(T) do {                                                             \
    const int* bp = bq + ((T) & 1) * 4096;                                       \
    int wv[8];                                                                   \
    _Pragma("unroll")                                                            \
    for (int j = 0; j < 8; ++j) wv[j] = bp[j * 128];                             \
    bf16x8 bfv = pack_b(wv);                                                     \
    acc0 = __builtin_amdgcn_mfma_f32_16x16x32_bf16(((T) & 1) ? aB0 : aA0, bfv, acc0, 0, 0, 0); \
    acc1 = __builtin_amdgcn_mfma_f32_16x16x32_bf16(((T) & 1) ? aB1 : aA1, bfv, acc1, 0, 0, 0); \
} while (0)

#define ITER(T) do { COMP(T); LOADA((T) + 1); __syncthreads(); STAGE((T) + 2); } while (0)

    // prologue: stage tiles 0,1; A(0) to regs; single drain barrier
    STAGE(0); STAGE(1); LOADA(0);
    __syncthreads();

    ITER(0);  ITER(1);  ITER(2);  ITER(3);
    ITER(4);  ITER(5);  ITER(6);  ITER(7);
    ITER(8);  ITER(9);  ITER(10); ITER(11);
    ITER(12); ITER(13); ITER(14);
    COMP(15);

#undef STAGE
#undef LOADA
#undef COMP
#undef ITER

    // Fused epilogue. C/D layout (HW-verified): row = 4*(lane>>4)+i, col = lane&15.
    const float sc = scale[n0w + c];
    float corr0[4] = {0.f, 0.f, 0.f, 0.f}, corr1[4] = {0.f, 0.f, 0.f, 0.f};
    if (blockIdx.y == 0) {
        const float zp = zero[n0w + c];
        #pragma unroll
        for (int i = 0; i < 4; ++i) {
            const int r = 4 * (lane >> 4) + i;
            corr0[i] = zp * rowsum[r];
            corr1[i] = zp * rowsum[16 + r];
        }
    }
    #pragma unroll
    for (int i = 0; i < 4; ++i) {
        const int r = 4 * (lane >> 4) + i;
        atomicAdd(&out[(size_t)r * N_DIM + n0w + c],        sc * (acc0[i] - corr0[i]));
        atomicAdd(&out[(size_t)(16 + r) * N_DIM + n0w + c], sc * (acc1[i] - corr1[i]));
    }
}

// ---------------------------------------------------------------------------
// Fallback path (ws too small; never expected with 768 MB ws).
// ---------------------------------------------------------------------------
__global__ __launch_bounds__(256) void qmm_zero_fb(float* __restrict__ out) {
    int i = blockIdx.x * 256 + threadIdx.x;
    ((float4*)out)[i] = make_float4(0.f, 0.f, 0.f, 0.f);
}
__global__ __launch_bounds__(256) void qmm_main_fb(const float* __restrict__ x,
                                                   const int* __restrict__ w,
                                                   float* __restrict__ out) {
    const int n  = blockIdx.x * 256 + threadIdx.x;
    const int k0 = blockIdx.y * 256;
    float acc[M_DIM];
    #pragma unroll
    for (int m = 0; m < M_DIM; ++m) acc[m] = 0.f;
    const int* wp = w + (size_t)k0 * N_DIM + n;
    for (int kk = 0; kk < 256; kk += 4) {
        const float w0 = (float)wp[(size_t)(kk + 0) * N_DIM];
        const float w1 = (float)wp[(size_t)(kk + 1) * N_DIM];
        const float w2 = (float)wp[(size_t)(kk + 2) * N_DIM];
        const float w3 = (float)wp[(size_t)(kk + 3) * N_DIM];
        #pragma unroll
        for (int m = 0; m < M_DIM; ++m) {
            const float4 xv = *(const float4*)(x + (size_t)m * K_DIM + k0 + kk);
            acc[m] = fmaf(xv.x, w0, fmaf(xv.y, w1, fmaf(xv.z, w2, fmaf(xv.w, w3, acc[m]))));
        }
    }
    #pragma unroll
    for (int m = 0; m < M_DIM; ++m)
        atomicAdd(&out[(size_t)m * N_DIM + n], acc[m]);
}
__global__ __launch_bounds__(256) void qmm_scale_fb(const float* __restrict__ x,
                                                    const float* __restrict__ scale,
                                                    const float* __restrict__ zero,
                                                    float* __restrict__ out) {
    const int m = blockIdx.y;
    __shared__ float red[256];
    float s = 0.f;
    for (int k = threadIdx.x; k < K_DIM; k += 256)
        s += x[(size_t)m * K_DIM + k];
    red[threadIdx.x] = s;
    __syncthreads();
    #pragma unroll
    for (int off = 128; off > 0; off >>= 1) {
        if (threadIdx.x < off) red[threadIdx.x] += red[threadIdx.x + off];
        __syncthreads();
    }
    const float rowsum = red[0];
    const int n = blockIdx.x * 256 + threadIdx.x;
    const float v = out[(size_t)m * N_DIM + n];
    out[(size_t)m * N_DIM + n] = scale[n] * (v - zero[n] * rowsum);
}

extern "C" void kernel_launch(void* const* d_in, const int* in_sizes, int n_in,
                              void* d_out, int out_size, void* d_ws, size_t ws_size,
                              hipStream_t stream) {
    const float* x     = (const float*)d_in[0];
    const int*   w     = (const int*)d_in[1];
    const float* scale = (const float*)d_in[2];   // fp16 in reference; harness delivers fp32
    const float* zero  = (const float*)d_in[3];
    float* out = (float*)d_out;

    const size_t frag_sz = (size_t)128 * 2 * 64 * 8 * sizeof(short);  // 256 KB
    short* fragp  = (short*)d_ws;
    float* rowsum = (float*)((char*)d_ws + frag_sz);

    if (ws_size >= frag_sz + 256) {
        qmm_prep<<<dim3(M_DIM * N_DIM / 4 / 256), dim3(256), 0, stream>>>(x, fragp, rowsum, out);
        qmm_main<<<dim3(N_DIM / NPB, SPLITK),     dim3(BLK), 0, stream>>>(fragp, w, rowsum, scale, zero, out);
    } else {
        qmm_zero_fb <<<dim3(M_DIM * N_DIM / 4 / 256), dim3(256), 0, stream>>>(out);
        qmm_main_fb <<<dim3(N_DIM / 256, 16),         dim3(256), 0, stream>>>(x, w, out);
        qmm_scale_fb<<<dim3(N_DIM / 256, M_DIM),      dim3(256), 0, stream>>>(x, scale, zero, out);
    }
}